// Round 18
// baseline (630.102 us; speedup 1.0000x reference)
//
#include <hip/hip_runtime.h>
#include <math.h>

#define B 16
#define N 1024
#define KNB 20

typedef unsigned int u32;
typedef unsigned long long u64;

__device__ __forceinline__ float sgnf(float v) {
    return (v > 0.f) ? 1.f : ((v < 0.f) ? -1.f : 0.f);
}

__global__ __launch_bounds__(256) void sentinel_kernel(float* __restrict__ out, int n, float v) {
    int i = blockIdx.x * blockDim.x + threadIdx.x;
    if (i < n) out[i] = v;
}

// ---------------- np-exact sq (UNCHANGED arithmetic) ----------------

template <int C>
__global__ __launch_bounds__(256) void sq_np_kernel(const float* __restrict__ x, int Ctot, int c0,
                                                    float* __restrict__ sq) {
    int i = blockIdx.x * blockDim.x + threadIdx.x;
    if (i >= B * N) return;
    int b = i >> 10, n = i & (N - 1);
    const float* xb = x + ((size_t)b * Ctot + c0) * N + n;
    float res;
    if (C < 8) {
        float v0 = xb[0];
        res = __fmul_rn(v0, v0);
        for (int c = 1; c < C; ++c) {
            float v = xb[(size_t)c * N];
            res = __fadd_rn(res, __fmul_rn(v, v));
        }
    } else {
        float r[8];
#pragma unroll
        for (int j = 0; j < 8; ++j) {
            float v = xb[(size_t)j * N];
            r[j] = __fmul_rn(v, v);
        }
        for (int c = 8; c < C; c += 8) {
#pragma unroll
            for (int j = 0; j < 8; ++j) {
                float v = xb[(size_t)(c + j) * N];
                r[j] = __fadd_rn(r[j], __fmul_rn(v, v));
            }
        }
        res = __fadd_rn(__fadd_rn(__fadd_rn(r[0], r[1]), __fadd_rn(r[2], r[3])),
                        __fadd_rn(__fadd_rn(r[4], r[5]), __fadd_rn(r[6], r[7])));
    }
    sq[i] = res;
}

// ---------------- knn: R15 structure + LDS-staged panel tiles ----------------
// 16 pts/block (4 waves, 4 pts/wave), XCD-swizzled grid; panel processed in 8-channel
// LDS tiles (coalesced float4 staging, conflict-free LDS MAC reads). np-exact distance
// chains (staging is a pure copy); top-20 SET radix select + stable ties (proven).
template <int C>
__global__ __launch_bounds__(256) void knn_radix4_kernel(const float* __restrict__ x, int Ctot,
                                                         int c0, const float* __restrict__ sq,
                                                         int* __restrict__ idxout) {
    const int id = blockIdx.x;
    const int swz = (id & 7) * 128 + (id >> 3);
    const int bx = swz & 63, b = swz >> 6;
    const int tid = threadIdx.x, wave = tid >> 6, lane = tid & 63;
    const int nbase = bx * 16;
    __shared__ float xn[C][16];
    __shared__ float xs[8][N];  // 32 KB panel tile
    const float* xb = x + ((size_t)b * Ctot + c0) * N;
    for (int t = tid; t < 16 * C; t += 256) {
        int pt = t & 15, c = t >> 4;
        xn[c][pt] = xb[(size_t)c * N + nbase + pt];
    }
    float acc[4][16];
#pragma unroll
    for (int p = 0; p < 4; ++p)
#pragma unroll
        for (int j = 0; j < 16; ++j) acc[p][j] = 0.f;
    const int w4 = wave * 4;
    const int NT = (C + 7) / 8;
    for (int ct = 0; ct < NT; ++ct) {
        const int c0t = ct * 8;
        const int rows = (C - c0t < 8) ? (C - c0t) : 8;
        __syncthreads();
        // cooperative coalesced staging: rows*256 float4s, 256 threads
        for (int t = tid; t < rows * 256; t += 256) {
            int cc = t >> 8, mm4 = t & 255;
            reinterpret_cast<float4*>(&xs[cc][0])[mm4] =
                reinterpret_cast<const float4*>(xb + (size_t)(c0t + cc) * N)[mm4];
        }
        __syncthreads();
        for (int cc = 0; cc < rows; ++cc) {
            const int c = c0t + cc;
            float xv0 = xn[c][w4 + 0], xv1 = xn[c][w4 + 1];
            float xv2 = xn[c][w4 + 2], xv3 = xn[c][w4 + 3];
            const float* row = &xs[cc][lane];
#pragma unroll
            for (int j = 0; j < 16; ++j) {
                float rv = row[j * 64];
                acc[0][j] = __fadd_rn(acc[0][j], __fmul_rn(xv0, rv));
                acc[1][j] = __fadd_rn(acc[1][j], __fmul_rn(xv1, rv));
                acc[2][j] = __fadd_rn(acc[2][j], __fmul_rn(xv2, rv));
                acc[3][j] = __fadd_rn(acc[3][j], __fmul_rn(xv3, rv));
            }
        }
    }
    float sqm[16];
#pragma unroll
    for (int j = 0; j < 16; ++j) sqm[j] = sq[b * N + j * 64 + lane];
    const u64 ltmask = (1ull << lane) - 1ull;
#pragma unroll
    for (int p = 0; p < 4; ++p) {
        const int n = nbase + w4 + p;
        const float sqn = sq[b * N + n];
        u32 key[16];
#pragma unroll
        for (int j = 0; j < 16; ++j) {
            float d = __fsub_rn(__fsub_rn(__fmul_rn(2.f, acc[p][j]), sqn), sqm[j]);
            u32 bits = __float_as_uint(d);
            if ((bits << 1) == 0) bits = 0;  // canonicalize -0 -> +0
            key[j] = (bits & 0x80000000u) ? ~bits : (bits | 0x80000000u);
        }
        u32 T = 0;
        for (int bpos = 31; bpos >= 0; --bpos) {
            u32 cand = T | (1u << bpos);
            int cnt = 0;
#pragma unroll
            for (int j = 0; j < 16; ++j) cnt += __popcll(__ballot(key[j] >= cand));
            if (cnt >= KNB) T = cand;
        }
        int* out = idxout + ((size_t)b * N + n) * KNB;
        int base = 0;
#pragma unroll
        for (int j = 0; j < 16; ++j) {
            u64 m = __ballot(key[j] > T);
            if (key[j] > T) out[base + __popcll(m & ltmask)] = j * 64 + lane;
            base += __popcll(m);
        }
        const int R = KNB - base;  // ties, filled ascending index (j asc, lane asc)
        int eqb = 0;
#pragma unroll
        for (int j = 0; j < 16; ++j) {
            u64 m = __ballot(key[j] == T);
            int r = eqb + __popcll(m & ltmask);
            if (key[j] == T && r < R) out[base + r] = j * 64 + lane;
            eqb += __popcll(m);
        }
    }
}

// ---------------- x0 -> row-major copy ----------------

__global__ __launch_bounds__(256) void transpose3_kernel(const float* __restrict__ x,
                                                         float* __restrict__ xT) {
    int i = blockIdx.x * blockDim.x + threadIdx.x;
    if (i >= B * N) return;
    int b = i >> 10, n = i & (N - 1);
    xT[(size_t)i * 3 + 0] = x[((size_t)b * 3 + 0) * N + n];
    xT[(size_t)i * 3 + 1] = x[((size_t)b * 3 + 1) * N + n];
    xT[(size_t)i * 3 + 2] = x[((size_t)b * 3 + 2) * N + n];
}

// ---------------- row-major [B][N][CO] -> xcat col-major slice ----------------

__global__ __launch_bounds__(256) void transpose_rm2cm_kernel(const float* __restrict__ yR, int CO,
                                                              float* __restrict__ xcat, int c0) {
    const int nb = blockIdx.x * 64, cb = blockIdx.y * 64, b = blockIdx.z;
    const int tid = threadIdx.x;
    __shared__ float t[64][65];
    for (int i = tid; i < 64 * 64; i += 256) {
        int nn = i >> 6, cc = i & 63;
        t[nn][cc] = yR[((size_t)(b * N + nb + nn)) * CO + cb + cc];
    }
    __syncthreads();
    for (int i = tid; i < 64 * 64; i += 256) {
        int cc = i >> 6, nn = i & 63;
        xcat[((size_t)b * 256 + c0 + cb + cc) * N + nb + nn] = t[nn][cc];
    }
}

// ---------------- layer-1 edgeconv (np-exact) ----------------

template <int C, int COUT>
__global__ __launch_bounds__(COUT) void edgeconv1_kernel(
    const float* __restrict__ xR, const int* __restrict__ idx, const float* __restrict__ W,
    const float* __restrict__ aa, const float* __restrict__ ssc, const float* __restrict__ bbi,
    const float* __restrict__ pp, float* __restrict__ yR, u32* __restrict__ xss,
    u32* __restrict__ xnzs, int woff) {
    const int b = blockIdx.y, n = blockIdx.x, tid = threadIdx.x;
    __shared__ float ctr_raw[C];
    __shared__ float df[C][KNB];
    __shared__ int ids[KNB];
    const float* xb = xR + (size_t)b * N * C;
    if (tid < KNB) ids[tid] = idx[((size_t)b * N + n) * KNB + tid];
    if (tid < C) ctr_raw[tid] = xb[(size_t)n * C + tid];
    __syncthreads();
    for (int t = tid; t < C * KNB; t += COUT) {
        int c = t / KNB, k = t - c * KNB;
        df[c][k] = __fsub_rn(xb[(size_t)ids[k] * C + c], ctr_raw[c]);
    }
    __syncthreads();
    const int o = tid;
    const float* wrow = W + (size_t)o * (2 * C);
    const float as = __fmul_rn(aa[o], ssc[o]);
    const float bo = bbi[o], po = pp[o];
    float best = -3.4e38f;
    float wd[C], wc[C];
    for (int c = 0; c < C; ++c) { wd[c] = sgnf(wrow[c]); wc[c] = sgnf(wrow[C + c]); }
    for (int k = 0; k < KNB; ++k) {
        float acc = 0.f;
        for (int c = 0; c < C; ++c) acc = __fadd_rn(acc, __fmul_rn(df[c][k], wd[c]));
        for (int c = 0; c < C; ++c) acc = __fadd_rn(acc, __fmul_rn(ctr_raw[c], wc[c]));
        float y = __fadd_rn(__fmul_rn(acc, as), bo);
        y = y > 0.f ? y : __fmul_rn(po, y);
        best = fmaxf(best, y);
    }
    yR[((size_t)b * N + n) * COUT + o] = best;
    u64 bs = __ballot(best < 0.f);
    u64 bnz = __ballot(best != 0.f);
    if ((tid & 63) == 0) {
        int w = woff + (tid >> 5);
        xss[(size_t)(b * 16 + w) * N + n] = (u32)bs;
        xss[(size_t)(b * 16 + w + 1) * N + n] = (u32)(bs >> 32);
        xnzs[(size_t)(b * 16 + w) * N + n] = (u32)bnz;
        xnzs[(size_t)(b * 16 + w + 1) * N + n] = (u32)(bnz >> 32);
    }
}

// ---------------- ternary weight / vector pack ----------------

__global__ __launch_bounds__(256) void pack_rows_kernel(const float* __restrict__ src, int rows,
                                                        int cols, u32* __restrict__ s,
                                                        u32* __restrict__ nz) {
    int i = blockIdx.x * blockDim.x + threadIdx.x;
    int wpr = cols >> 5;
    if (i >= rows * wpr) return;
    int r = i / wpr, w = i - r * wpr;
    const float* p = src + (size_t)r * cols + (size_t)w * 32;
    u32 sb = 0, nb = 0;
    for (int j = 0; j < 32; ++j) {
        float v = p[j];
        if (v < 0.f) sb |= (1u << j);
        if (v != 0.f) nb |= (1u << j);
    }
    s[i] = sb;
    nz[i] = nb;
}

// ---------------- binarized edgeconv (UNCHANGED) ----------------

template <int C, int COUT, bool WRITEF>
__global__ __launch_bounds__(COUT) void edgeconv_bin2_kernel(
    const float* __restrict__ xR, const int* __restrict__ idx, const u32* __restrict__ wsm,
    const u32* __restrict__ wnzm, const float* __restrict__ aa, const float* __restrict__ ssc,
    const float* __restrict__ bbi, const float* __restrict__ pp, float* __restrict__ yR,
    u32* __restrict__ xss, u32* __restrict__ xnzs, int woff) {
    constexpr int W = C / 32;
    const int b = blockIdx.y, n = blockIdx.x, tid = threadIdx.x;
    __shared__ float ctr_raw[C];
    __shared__ int ids[KNB];
    __shared__ u32 ctr_s[W], ctr_nz[W];
    __shared__ u32 dfs[KNB][W], dfnz[KNB][W];
    const float* xb = xR + (size_t)b * N * C;
    if (tid < KNB) ids[tid] = idx[((size_t)b * N + n) * KNB + tid];
    if (tid < C) {
        float v = xb[(size_t)n * C + tid];
        ctr_raw[tid] = v;
        u64 bs = __ballot(v < 0.f);
        u64 bnz = __ballot(v != 0.f);
        if ((tid & 63) == 0) {
            int wb = tid >> 5;
            ctr_s[wb] = (u32)bs;       ctr_s[wb + 1] = (u32)(bs >> 32);
            ctr_nz[wb] = (u32)bnz;     ctr_nz[wb + 1] = (u32)(bnz >> 32);
        }
    }
    __syncthreads();
    for (int t = tid; t < KNB * C; t += COUT) {
        int k = t / C, c = t - k * C;
        float v = __fsub_rn(xb[(size_t)ids[k] * C + c], ctr_raw[c]);
        u64 bs = __ballot(v < 0.f);
        u64 bnz = __ballot(v != 0.f);
        if ((c & 63) == 0) {
            int wb = c >> 5;
            dfs[k][wb] = (u32)bs;      dfs[k][wb + 1] = (u32)(bs >> 32);
            dfnz[k][wb] = (u32)bnz;    dfnz[k][wb + 1] = (u32)(bnz >> 32);
        }
    }
    __syncthreads();
    const int o = tid;
    const u32* wsrow = wsm + (size_t)o * 2 * W;
    const u32* wnzrow = wnzm + (size_t)o * 2 * W;
    u32 wds[W], wdnz[W], wcs[W], wcnz[W];
#pragma unroll
    for (int w = 0; w < W; ++w) {
        wds[w] = wsrow[w];      wcs[w] = wsrow[W + w];
        wdnz[w] = wnzrow[w];    wcnz[w] = wnzrow[W + w];
    }
    int cdot = 0;
#pragma unroll
    for (int w = 0; w < W; ++w) {
        u32 nzb = ctr_nz[w] & wcnz[w];
        u32 neg = (ctr_s[w] ^ wcs[w]) & nzb;
        cdot += __popc(nzb) - 2 * __popc(neg);
    }
    const float as = __fmul_rn(aa[o], ssc[o]);
    const float bo = bbi[o], po = pp[o];
    float best = -3.4e38f;
    for (int k = 0; k < KNB; ++k) {
        int dot = cdot;
#pragma unroll
        for (int w = 0; w < W; ++w) {
            u32 nzb = dfnz[k][w] & wdnz[w];
            u32 neg = (dfs[k][w] ^ wds[w]) & nzb;
            dot += __popc(nzb) - 2 * __popc(neg);
        }
        float y = __fadd_rn(__fmul_rn((float)dot, as), bo);
        y = y > 0.f ? y : __fmul_rn(po, y);
        best = fmaxf(best, y);
    }
    if (WRITEF) yR[((size_t)b * N + n) * COUT + o] = best;
    u64 bs = __ballot(best < 0.f);
    u64 bnz = __ballot(best != 0.f);
    if ((tid & 63) == 0) {
        int w = woff + (tid >> 5);
        xss[(size_t)(b * 16 + w) * N + n] = (u32)bs;
        xss[(size_t)(b * 16 + w + 1) * N + n] = (u32)(bs >> 32);
        xnzs[(size_t)(b * 16 + w) * N + n] = (u32)bnz;
        xnzs[(size_t)(b * 16 + w + 1) * N + n] = (u32)(bnz >> 32);
    }
}

// ---------------- conv1d bitplane popcount + fused pooling ----------------

__global__ __launch_bounds__(256) void conv1d_bin_pool_kernel(
    const u32* __restrict__ xs, const u32* __restrict__ xnz, const u32* __restrict__ w5s,
    const u32* __restrict__ w5nz, const float* __restrict__ aa, const float* __restrict__ ssc,
    const float* __restrict__ bbi, const float* __restrict__ pp, float* __restrict__ pmax,
    float* __restrict__ psum) {
    const int b = blockIdx.y;
    const int otile = blockIdx.x & 3;
    const int nq = blockIdx.x >> 2;  // 0..15
    const int tid = threadIdx.x;
    const int o = otile * 256 + tid;
    __shared__ u32 shs[64][21];
    __shared__ u32 shnz[64][21];
    u32 ws[16], wnz[16];
#pragma unroll
    for (int w = 0; w < 16; ++w) {
        ws[w] = w5s[(size_t)o * 16 + w];
        wnz[w] = w5nz[(size_t)o * 16 + w];
    }
    const int nbase = nq * 64;
    for (int t = tid; t < 16 * 64; t += 256) {
        int w = t >> 6, nl = t & 63;
        shs[nl][w] = xs[((size_t)b * 16 + w) * N + nbase + nl];
        shnz[nl][w] = xnz[((size_t)b * 16 + w) * N + nbase + nl];
    }
    __syncthreads();
    const float as = __fmul_rn(aa[o], ssc[o]);
    const float bo = bbi[o], po = pp[o];
    float m = -3.4e38f, sum = 0.f;
    for (int nl = 0; nl < 64; ++nl) {
        int dot = 0;
#pragma unroll
        for (int w = 0; w < 16; ++w) {
            u32 nzb = shnz[nl][w] & wnz[w];
            u32 neg = (shs[nl][w] ^ ws[w]) & nzb;
            dot += __popc(nzb) - 2 * __popc(neg);
        }
        float y = __fadd_rn(__fmul_rn((float)dot, as), bo);
        y = y > 0.f ? y : __fmul_rn(po, y);
        m = fmaxf(m, y);
        sum = __fadd_rn(sum, y);  // exact: quarter-integers
    }
    pmax[((size_t)b * 1024 + o) * 16 + nq] = m;
    psum[((size_t)b * 1024 + o) * 16 + nq] = sum;
}

__global__ __launch_bounds__(256) void pool_reduce_kernel(const float* __restrict__ pmax,
                                                          const float* __restrict__ psum,
                                                          float* __restrict__ pooled) {
    int i = blockIdx.x * blockDim.x + threadIdx.x;
    if (i >= B * 1024) return;
    int b = i >> 10, o = i & 1023;
    const float* pm = pmax + (size_t)i * 16;
    const float* ps = psum + (size_t)i * 16;
    float m = -3.4e38f, s = 0.f;
    for (int t = 0; t < 16; ++t) { m = fmaxf(m, pm[t]); s = __fadd_rn(s, ps[t]); }
    pooled[(size_t)b * 2048 + o] = m;
    pooled[(size_t)b * 2048 + 1024 + o] = __fmul_rn(s, (1.f / 1024.f));
}

// pack pooled (B x 2048) into ternary bitplanes: B x 64 words
__global__ __launch_bounds__(256) void pack_pooled_kernel(const float* __restrict__ pooled,
                                                          u32* __restrict__ s,
                                                          u32* __restrict__ nz) {
    int i = blockIdx.x * blockDim.x + threadIdx.x;
    if (i >= B * 64) return;
    const float* p = pooled + (size_t)i * 32;
    u32 sb = 0, nb = 0;
    for (int j = 0; j < 32; ++j) {
        float v = p[j];
        if (v < 0.f) sb |= (1u << j);
        if (v != 0.f) nb |= (1u << j);
    }
    s[i] = sb;
    nz[i] = nb;
}

// ---------------- bitpacked lin1 / lin2 / lin3 (UNCHANGED) ----------------

__global__ __launch_bounds__(256) void lin1_bin_kernel(
    const u32* __restrict__ xs, const u32* __restrict__ xnz, const u32* __restrict__ wls,
    const u32* __restrict__ wlnz, const float* __restrict__ aa, const float* __restrict__ ssc,
    const float* __restrict__ bbi, const float* __restrict__ pp, u32* __restrict__ l1s,
    u32* __restrict__ l1nz) {
    const int b = blockIdx.y, otile = blockIdx.x, tid = threadIdx.x;
    const int o = otile * 256 + tid;
    __shared__ u32 sxs[64], sxnz[64];
    if (tid < 64) { sxs[tid] = xs[b * 64 + tid]; sxnz[tid] = xnz[b * 64 + tid]; }
    __syncthreads();
    const u32* wsr = wls + (size_t)o * 64;
    const u32* wnzr = wlnz + (size_t)o * 64;
    int dot = 0;
#pragma unroll
    for (int w = 0; w < 64; ++w) {
        u32 nzb = sxnz[w] & wnzr[w];
        u32 neg = (sxs[w] ^ wsr[w]) & nzb;
        dot += __popc(nzb) - 2 * __popc(neg);
    }
    float y = __fadd_rn(__fmul_rn((float)dot, __fmul_rn(aa[o], ssc[o])), bbi[o]);
    y = y > 0.f ? y : __fmul_rn(pp[o], y);
    u64 bs = __ballot(y < 0.f);
    u64 bnz = __ballot(y != 0.f);
    if ((tid & 63) == 0) {
        int w = otile * 8 + (tid >> 5);
        l1s[b * 16 + w] = (u32)bs;       l1s[b * 16 + w + 1] = (u32)(bs >> 32);
        l1nz[b * 16 + w] = (u32)bnz;     l1nz[b * 16 + w + 1] = (u32)(bnz >> 32);
    }
}

__global__ __launch_bounds__(256) void lin2_bin_kernel(
    const u32* __restrict__ xs, const u32* __restrict__ xnz, const u32* __restrict__ wls,
    const u32* __restrict__ wlnz, const float* __restrict__ aa, const float* __restrict__ ssc,
    const float* __restrict__ bbi, const float* __restrict__ pp, float* __restrict__ out) {
    const int b = blockIdx.x, o = threadIdx.x;
    __shared__ u32 sxs[16], sxnz[16];
    if (o < 16) { sxs[o] = xs[b * 16 + o]; sxnz[o] = xnz[b * 16 + o]; }
    __syncthreads();
    const u32* wsr = wls + (size_t)o * 16;
    const u32* wnzr = wlnz + (size_t)o * 16;
    int dot = 0;
#pragma unroll
    for (int w = 0; w < 16; ++w) {
        u32 nzb = sxnz[w] & wnzr[w];
        u32 neg = (sxs[w] ^ wsr[w]) & nzb;
        dot += __popc(nzb) - 2 * __popc(neg);
    }
    float y = __fadd_rn(__fmul_rn((float)dot, __fmul_rn(aa[o], ssc[o])), bbi[o]);
    out[b * 256 + o] = y > 0.f ? y : __fmul_rn(pp[o], y);
}

__global__ __launch_bounds__(64) void lin3_kernel(const float* __restrict__ xin,
                                                  const float* __restrict__ W,
                                                  const float* __restrict__ ssc,
                                                  const float* __restrict__ bbi,
                                                  float* __restrict__ out) {
    int b = blockIdx.x, j = threadIdx.x;
    if (j >= 40) return;
    const float* wrow = W + j * 256;
    const float* xb = xin + b * 256;
    double acc = 0.0;
    for (int c = 0; c < 256; ++c) acc = fma((double)xb[c], (double)wrow[c], acc);
    out[b * 40 + j] = __fadd_rn(__fmul_rn((float)acc, ssc[j]), bbi[j]);
}

extern "C" void kernel_launch(void* const* d_in, const int* in_sizes, int n_in, void* d_out,
                              int out_size, void* d_ws, size_t ws_size, hipStream_t stream) {
    float* outp = (float*)d_out;
    auto sentinel = [&](float code) {
        sentinel_kernel<<<(640 + 255) / 256, 256, 0, stream>>>(outp, 640, code * 1.0e6f);
    };
    if (n_in != 39) { sentinel(1.f); return; }
    static const int expect[39] = {
        16 * 3 * 1024,
        64 * 6, 64, 64, 64, 64,
        64 * 128, 64, 64, 64, 64,
        128 * 128, 128, 128, 128, 128,
        256 * 256, 256, 256, 256, 256,
        1024 * 512, 1024, 1024, 1024, 1024,
        512 * 2048, 512, 512, 512, 512,
        256 * 512, 256, 256, 256, 256,
        40 * 256, 40, 40
    };
    for (int i = 0; i < 39; ++i)
        if (in_sizes[i] != expect[i]) { sentinel(2.f); return; }
    if (out_size != 640) { sentinel(3.f); return; }

    const float* x0 = (const float*)d_in[0];
    const float *w1 = (const float*)d_in[1], *a1 = (const float*)d_in[2],
                *s1 = (const float*)d_in[3], *b1 = (const float*)d_in[4],
                *p1 = (const float*)d_in[5];
    const float *a2 = (const float*)d_in[7], *s2 = (const float*)d_in[8],
                *b2 = (const float*)d_in[9], *p2 = (const float*)d_in[10];
    const float *a3 = (const float*)d_in[12], *s3 = (const float*)d_in[13],
                *b3 = (const float*)d_in[14], *p3 = (const float*)d_in[15];
    const float *a4 = (const float*)d_in[17], *s4 = (const float*)d_in[18],
                *b4 = (const float*)d_in[19], *p4 = (const float*)d_in[20];
    const float *a5 = (const float*)d_in[22], *s5 = (const float*)d_in[23],
                *b5 = (const float*)d_in[24], *p5 = (const float*)d_in[25];
    const float *w2 = (const float*)d_in[6], *w3 = (const float*)d_in[11],
                *w4 = (const float*)d_in[16], *w5 = (const float*)d_in[21];
    const float *wl1 = (const float*)d_in[26], *al1 = (const float*)d_in[27],
                *sl1 = (const float*)d_in[28], *bl1 = (const float*)d_in[29],
                *pl1 = (const float*)d_in[30];
    const float *wl2 = (const float*)d_in[31], *al2 = (const float*)d_in[32],
                *sl2 = (const float*)d_in[33], *bl2 = (const float*)d_in[34],
                *pl2 = (const float*)d_in[35];
    const float *wl3 = (const float*)d_in[36], *sl3 = (const float*)d_in[37],
                *bl3 = (const float*)d_in[38];

    char* ws = (char*)d_ws;
    size_t off = 0;
    auto alloc = [&](size_t bytes) -> void* {
        void* p = ws + off;
        off += (bytes + 255) & ~(size_t)255;
        return p;
    };
    float* xcat = (float*)alloc((size_t)B * 256 * N * 4);
    float* yA = (float*)alloc((size_t)B * N * 128 * 4);
    float* yB = (float*)alloc((size_t)B * N * 64 * 4);
    float* x0R = (float*)alloc((size_t)B * N * 3 * 4);
    int* idxb = (int*)alloc((size_t)B * N * KNB * 4);
    float* sqb = (float*)alloc((size_t)B * N * 4);
    u32* w2s_ = (u32*)alloc(64 * 4 * 4);     u32* w2nz_ = (u32*)alloc(64 * 4 * 4);
    u32* w3s_ = (u32*)alloc(128 * 4 * 4);    u32* w3nz_ = (u32*)alloc(128 * 4 * 4);
    u32* w4s_ = (u32*)alloc(256 * 8 * 4);    u32* w4nz_ = (u32*)alloc(256 * 8 * 4);
    u32* w5s_ = (u32*)alloc(1024 * 16 * 4);  u32* w5nz_ = (u32*)alloc(1024 * 16 * 4);
    u32* wl1s_ = (u32*)alloc(512 * 64 * 4);  u32* wl1nz_ = (u32*)alloc(512 * 64 * 4);
    u32* wl2s_ = (u32*)alloc(256 * 16 * 4);  u32* wl2nz_ = (u32*)alloc(256 * 16 * 4);
    u32* xss = (u32*)alloc((size_t)B * 16 * N * 4);
    u32* xnzs = (u32*)alloc((size_t)B * 16 * N * 4);
    u32* pls = (u32*)alloc((size_t)B * 64 * 4);
    u32* plnz = (u32*)alloc((size_t)B * 64 * 4);
    u32* l1s = (u32*)alloc((size_t)B * 16 * 4);
    u32* l1nz = (u32*)alloc((size_t)B * 16 * 4);
    float* pmax = (float*)alloc((size_t)B * 1024 * 16 * 4);
    float* psum = (float*)alloc((size_t)B * 1024 * 16 * 4);
    float* pooled = (float*)alloc((size_t)B * 2048 * 4);
    float* l2o = (float*)alloc((size_t)B * 256 * 4);
    if (off > ws_size) { sentinel(4.f); return; }

    pack_rows_kernel<<<1, 256, 0, stream>>>(w2, 64, 128, w2s_, w2nz_);
    pack_rows_kernel<<<2, 256, 0, stream>>>(w3, 128, 128, w3s_, w3nz_);
    pack_rows_kernel<<<8, 256, 0, stream>>>(w4, 256, 256, w4s_, w4nz_);
    pack_rows_kernel<<<64, 256, 0, stream>>>(w5, 1024, 512, w5s_, w5nz_);
    pack_rows_kernel<<<128, 256, 0, stream>>>(wl1, 512, 2048, wl1s_, wl1nz_);
    pack_rows_kernel<<<16, 256, 0, stream>>>(wl2, 256, 512, wl2s_, wl2nz_);

    dim3 gnb(N, B);
    const int gknn = (N / 16) * B;  // 1024 blocks, XCD-swizzled inside the kernel
    const int npt = (B * N + 255) / 256;
    // ---- layer 1 ----
    sq_np_kernel<3><<<npt, 256, 0, stream>>>(x0, 3, 0, sqb);
    transpose3_kernel<<<npt, 256, 0, stream>>>(x0, x0R);
    knn_radix4_kernel<3><<<gknn, 256, 0, stream>>>(x0, 3, 0, sqb, idxb);
    edgeconv1_kernel<3, 64>
        <<<gnb, 64, 0, stream>>>(x0R, idxb, w1, a1, s1, b1, p1, yA, xss, xnzs, 0);
    transpose_rm2cm_kernel<<<dim3(16, 1, B), 256, 0, stream>>>(yA, 64, xcat, 0);
    // ---- layer 2 ----
    sq_np_kernel<64><<<npt, 256, 0, stream>>>(xcat, 256, 0, sqb);
    knn_radix4_kernel<64><<<gknn, 256, 0, stream>>>(xcat, 256, 0, sqb, idxb);
    edgeconv_bin2_kernel<64, 64, true>
        <<<gnb, 64, 0, stream>>>(yA, idxb, w2s_, w2nz_, a2, s2, b2, p2, yB, xss, xnzs, 2);
    transpose_rm2cm_kernel<<<dim3(16, 1, B), 256, 0, stream>>>(yB, 64, xcat, 64);
    // ---- layer 3 ----
    sq_np_kernel<64><<<npt, 256, 0, stream>>>(xcat, 256, 64, sqb);
    knn_radix4_kernel<64><<<gknn, 256, 0, stream>>>(xcat, 256, 64, sqb, idxb);
    edgeconv_bin2_kernel<64, 128, true>
        <<<gnb, 128, 0, stream>>>(yB, idxb, w3s_, w3nz_, a3, s3, b3, p3, yA, xss, xnzs, 4);
    transpose_rm2cm_kernel<<<dim3(16, 2, B), 256, 0, stream>>>(yA, 128, xcat, 128);
    // ---- layer 4 ----
    sq_np_kernel<128><<<npt, 256, 0, stream>>>(xcat, 256, 128, sqb);
    knn_radix4_kernel<128><<<gknn, 256, 0, stream>>>(xcat, 256, 128, sqb, idxb);
    edgeconv_bin2_kernel<128, 256, false>
        <<<gnb, 256, 0, stream>>>(yA, idxb, w4s_, w4nz_, a4, s4, b4, p4, nullptr, xss, xnzs, 8);
    // ---- conv1d + pooling + heads ----
    conv1d_bin_pool_kernel<<<dim3(64, B), 256, 0, stream>>>(xss, xnzs, w5s_, w5nz_, a5, s5, b5,
                                                            p5, pmax, psum);
    pool_reduce_kernel<<<(B * 1024 + 255) / 256, 256, 0, stream>>>(pmax, psum, pooled);
    pack_pooled_kernel<<<(B * 64 + 255) / 256, 256, 0, stream>>>(pooled, pls, plnz);
    lin1_bin_kernel<<<dim3(2, B), 256, 0, stream>>>(pls, plnz, wl1s_, wl1nz_, al1, sl1, bl1, pl1,
                                                    l1s, l1nz);
    lin2_bin_kernel<<<B, 256, 0, stream>>>(l1s, l1nz, wl2s_, wl2nz_, al2, sl2, bl2, pl2, l2o);
    lin3_kernel<<<B, 64, 0, stream>>>(l2o, wl3, sl3, bl3, outp);
}

// Round 19
// 518.012 us; speedup vs baseline: 1.2164x; 1.2164x over previous
//
#include <hip/hip_runtime.h>
#include <math.h>

#define B 16
#define N 1024
#define KNB 20

typedef unsigned int u32;
typedef unsigned long long u64;

__device__ __forceinline__ float sgnf(float v) {
    return (v > 0.f) ? 1.f : ((v < 0.f) ? -1.f : 0.f);
}

__global__ __launch_bounds__(256) void sentinel_kernel(float* __restrict__ out, int n, float v) {
    int i = blockIdx.x * blockDim.x + threadIdx.x;
    if (i < n) out[i] = v;
}

// ---------------- np-exact sq (UNCHANGED arithmetic) ----------------

template <int C>
__global__ __launch_bounds__(256) void sq_np_kernel(const float* __restrict__ x, int Ctot, int c0,
                                                    float* __restrict__ sq) {
    int i = blockIdx.x * blockDim.x + threadIdx.x;
    if (i >= B * N) return;
    int b = i >> 10, n = i & (N - 1);
    const float* xb = x + ((size_t)b * Ctot + c0) * N + n;
    float res;
    if (C < 8) {
        float v0 = xb[0];
        res = __fmul_rn(v0, v0);
        for (int c = 1; c < C; ++c) {
            float v = xb[(size_t)c * N];
            res = __fadd_rn(res, __fmul_rn(v, v));
        }
    } else {
        float r[8];
#pragma unroll
        for (int j = 0; j < 8; ++j) {
            float v = xb[(size_t)j * N];
            r[j] = __fmul_rn(v, v);
        }
        for (int c = 8; c < C; c += 8) {
#pragma unroll
            for (int j = 0; j < 8; ++j) {
                float v = xb[(size_t)(c + j) * N];
                r[j] = __fadd_rn(r[j], __fmul_rn(v, v));
            }
        }
        res = __fadd_rn(__fadd_rn(__fadd_rn(r[0], r[1]), __fadd_rn(r[2], r[3])),
                        __fadd_rn(__fadd_rn(r[4], r[5]), __fadd_rn(r[6], r[7])));
    }
    sq[i] = res;
}

// ---------------- knn: R15 structure (best measured) + early-exit radix select ----------------
// 16 pts/block (4 waves, 4 pts/wave), j*64+lane scattered loads, XCD-swizzled grid.
// np-exact distances. Top-20 SET via radix threshold: early exit when cnt==KNB
// (the set {key >= T_prefix} is then exactly the top-20 set; emission order is
// irrelevant downstream). Ties -> lowest index (stable-top-k set semantics).
template <int C>
__global__ __launch_bounds__(256) void knn_radix4_kernel(const float* __restrict__ x, int Ctot,
                                                         int c0, const float* __restrict__ sq,
                                                         int* __restrict__ idxout) {
    const int id = blockIdx.x;
    const int swz = (id & 7) * 128 + (id >> 3);
    const int bx = swz & 63, b = swz >> 6;
    const int tid = threadIdx.x, wave = tid >> 6, lane = tid & 63;
    const int nbase = bx * 16;
    __shared__ float xn[C][16];
    const float* xb = x + ((size_t)b * Ctot + c0) * N;
    for (int t = tid; t < 16 * C; t += 256) {
        int pt = t & 15, c = t >> 4;
        xn[c][pt] = xb[(size_t)c * N + nbase + pt];
    }
    __syncthreads();
    float acc[4][16];
#pragma unroll
    for (int p = 0; p < 4; ++p)
#pragma unroll
        for (int j = 0; j < 16; ++j) acc[p][j] = 0.f;
    const int w4 = wave * 4;
    for (int c = 0; c < C; ++c) {
        const float* row = xb + (size_t)c * N + lane;
        float xv0 = xn[c][w4 + 0], xv1 = xn[c][w4 + 1];
        float xv2 = xn[c][w4 + 2], xv3 = xn[c][w4 + 3];
#pragma unroll
        for (int j = 0; j < 16; ++j) {
            float rv = row[j * 64];
            acc[0][j] = __fadd_rn(acc[0][j], __fmul_rn(xv0, rv));
            acc[1][j] = __fadd_rn(acc[1][j], __fmul_rn(xv1, rv));
            acc[2][j] = __fadd_rn(acc[2][j], __fmul_rn(xv2, rv));
            acc[3][j] = __fadd_rn(acc[3][j], __fmul_rn(xv3, rv));
        }
    }
    float sqm[16];
#pragma unroll
    for (int j = 0; j < 16; ++j) sqm[j] = sq[b * N + j * 64 + lane];
    const u64 ltmask = (1ull << lane) - 1ull;
#pragma unroll
    for (int p = 0; p < 4; ++p) {
        const int n = nbase + w4 + p;
        const float sqn = sq[b * N + n];
        u32 key[16];
#pragma unroll
        for (int j = 0; j < 16; ++j) {
            float d = __fsub_rn(__fsub_rn(__fmul_rn(2.f, acc[p][j]), sqn), sqm[j]);
            u32 bits = __float_as_uint(d);
            if ((bits << 1) == 0) bits = 0;  // canonicalize -0 -> +0
            key[j] = (bits & 0x80000000u) ? ~bits : (bits | 0x80000000u);
        }
        // radix descend with early exit: stop once {key >= T} has exactly KNB members
        u32 T = 0;
        for (int bpos = 31; bpos >= 0; --bpos) {
            u32 cand = T | (1u << bpos);
            int cnt = 0;
#pragma unroll
            for (int j = 0; j < 16; ++j) cnt += __popcll(__ballot(key[j] >= cand));
            if (cnt >= KNB) {
                T = cand;
                if (cnt == KNB) break;  // set isolated exactly; ties below T impossible to enter
            }
        }
        int* out = idxout + ((size_t)b * N + n) * KNB;
        int base = 0;
#pragma unroll
        for (int j = 0; j < 16; ++j) {
            u64 m = __ballot(key[j] > T);
            if (key[j] > T) out[base + __popcll(m & ltmask)] = j * 64 + lane;
            base += __popcll(m);
        }
        const int R = KNB - base;  // ties, filled ascending index (j asc, lane asc)
        if (R > 0) {
            int eqb = 0;
#pragma unroll
            for (int j = 0; j < 16; ++j) {
                u64 m = __ballot(key[j] == T);
                int r = eqb + __popcll(m & ltmask);
                if (key[j] == T && r < R) out[base + r] = j * 64 + lane;
                eqb += __popcll(m);
            }
        }
    }
}

// ---------------- x0 -> row-major copy ----------------

__global__ __launch_bounds__(256) void transpose3_kernel(const float* __restrict__ x,
                                                         float* __restrict__ xT) {
    int i = blockIdx.x * blockDim.x + threadIdx.x;
    if (i >= B * N) return;
    int b = i >> 10, n = i & (N - 1);
    xT[(size_t)i * 3 + 0] = x[((size_t)b * 3 + 0) * N + n];
    xT[(size_t)i * 3 + 1] = x[((size_t)b * 3 + 1) * N + n];
    xT[(size_t)i * 3 + 2] = x[((size_t)b * 3 + 2) * N + n];
}

// ---------------- row-major [B][N][CO] -> xcat col-major slice ----------------

__global__ __launch_bounds__(256) void transpose_rm2cm_kernel(const float* __restrict__ yR, int CO,
                                                              float* __restrict__ xcat, int c0) {
    const int nb = blockIdx.x * 64, cb = blockIdx.y * 64, b = blockIdx.z;
    const int tid = threadIdx.x;
    __shared__ float t[64][65];
    for (int i = tid; i < 64 * 64; i += 256) {
        int nn = i >> 6, cc = i & 63;
        t[nn][cc] = yR[((size_t)(b * N + nb + nn)) * CO + cb + cc];
    }
    __syncthreads();
    for (int i = tid; i < 64 * 64; i += 256) {
        int cc = i >> 6, nn = i & 63;
        xcat[((size_t)b * 256 + c0 + cb + cc) * N + nb + nn] = t[nn][cc];
    }
}

// ---------------- layer-1 edgeconv (np-exact) ----------------

template <int C, int COUT>
__global__ __launch_bounds__(COUT) void edgeconv1_kernel(
    const float* __restrict__ xR, const int* __restrict__ idx, const float* __restrict__ W,
    const float* __restrict__ aa, const float* __restrict__ ssc, const float* __restrict__ bbi,
    const float* __restrict__ pp, float* __restrict__ yR, u32* __restrict__ xss,
    u32* __restrict__ xnzs, int woff) {
    const int b = blockIdx.y, n = blockIdx.x, tid = threadIdx.x;
    __shared__ float ctr_raw[C];
    __shared__ float df[C][KNB];
    __shared__ int ids[KNB];
    const float* xb = xR + (size_t)b * N * C;
    if (tid < KNB) ids[tid] = idx[((size_t)b * N + n) * KNB + tid];
    if (tid < C) ctr_raw[tid] = xb[(size_t)n * C + tid];
    __syncthreads();
    for (int t = tid; t < C * KNB; t += COUT) {
        int c = t / KNB, k = t - c * KNB;
        df[c][k] = __fsub_rn(xb[(size_t)ids[k] * C + c], ctr_raw[c]);
    }
    __syncthreads();
    const int o = tid;
    const float* wrow = W + (size_t)o * (2 * C);
    const float as = __fmul_rn(aa[o], ssc[o]);
    const float bo = bbi[o], po = pp[o];
    float best = -3.4e38f;
    float wd[C], wc[C];
    for (int c = 0; c < C; ++c) { wd[c] = sgnf(wrow[c]); wc[c] = sgnf(wrow[C + c]); }
    for (int k = 0; k < KNB; ++k) {
        float acc = 0.f;
        for (int c = 0; c < C; ++c) acc = __fadd_rn(acc, __fmul_rn(df[c][k], wd[c]));
        for (int c = 0; c < C; ++c) acc = __fadd_rn(acc, __fmul_rn(ctr_raw[c], wc[c]));
        float y = __fadd_rn(__fmul_rn(acc, as), bo);
        y = y > 0.f ? y : __fmul_rn(po, y);
        best = fmaxf(best, y);
    }
    yR[((size_t)b * N + n) * COUT + o] = best;
    u64 bs = __ballot(best < 0.f);
    u64 bnz = __ballot(best != 0.f);
    if ((tid & 63) == 0) {
        int w = woff + (tid >> 5);
        xss[(size_t)(b * 16 + w) * N + n] = (u32)bs;
        xss[(size_t)(b * 16 + w + 1) * N + n] = (u32)(bs >> 32);
        xnzs[(size_t)(b * 16 + w) * N + n] = (u32)bnz;
        xnzs[(size_t)(b * 16 + w + 1) * N + n] = (u32)(bnz >> 32);
    }
}

// ---------------- ternary weight / vector pack ----------------

__global__ __launch_bounds__(256) void pack_rows_kernel(const float* __restrict__ src, int rows,
                                                        int cols, u32* __restrict__ s,
                                                        u32* __restrict__ nz) {
    int i = blockIdx.x * blockDim.x + threadIdx.x;
    int wpr = cols >> 5;
    if (i >= rows * wpr) return;
    int r = i / wpr, w = i - r * wpr;
    const float* p = src + (size_t)r * cols + (size_t)w * 32;
    u32 sb = 0, nb = 0;
    for (int j = 0; j < 32; ++j) {
        float v = p[j];
        if (v < 0.f) sb |= (1u << j);
        if (v != 0.f) nb |= (1u << j);
    }
    s[i] = sb;
    nz[i] = nb;
}

// ---------------- binarized edgeconv (UNCHANGED) ----------------

template <int C, int COUT, bool WRITEF>
__global__ __launch_bounds__(COUT) void edgeconv_bin2_kernel(
    const float* __restrict__ xR, const int* __restrict__ idx, const u32* __restrict__ wsm,
    const u32* __restrict__ wnzm, const float* __restrict__ aa, const float* __restrict__ ssc,
    const float* __restrict__ bbi, const float* __restrict__ pp, float* __restrict__ yR,
    u32* __restrict__ xss, u32* __restrict__ xnzs, int woff) {
    constexpr int W = C / 32;
    const int b = blockIdx.y, n = blockIdx.x, tid = threadIdx.x;
    __shared__ float ctr_raw[C];
    __shared__ int ids[KNB];
    __shared__ u32 ctr_s[W], ctr_nz[W];
    __shared__ u32 dfs[KNB][W], dfnz[KNB][W];
    const float* xb = xR + (size_t)b * N * C;
    if (tid < KNB) ids[tid] = idx[((size_t)b * N + n) * KNB + tid];
    if (tid < C) {
        float v = xb[(size_t)n * C + tid];
        ctr_raw[tid] = v;
        u64 bs = __ballot(v < 0.f);
        u64 bnz = __ballot(v != 0.f);
        if ((tid & 63) == 0) {
            int wb = tid >> 5;
            ctr_s[wb] = (u32)bs;       ctr_s[wb + 1] = (u32)(bs >> 32);
            ctr_nz[wb] = (u32)bnz;     ctr_nz[wb + 1] = (u32)(bnz >> 32);
        }
    }
    __syncthreads();
    for (int t = tid; t < KNB * C; t += COUT) {
        int k = t / C, c = t - k * C;
        float v = __fsub_rn(xb[(size_t)ids[k] * C + c], ctr_raw[c]);
        u64 bs = __ballot(v < 0.f);
        u64 bnz = __ballot(v != 0.f);
        if ((c & 63) == 0) {
            int wb = c >> 5;
            dfs[k][wb] = (u32)bs;      dfs[k][wb + 1] = (u32)(bs >> 32);
            dfnz[k][wb] = (u32)bnz;    dfnz[k][wb + 1] = (u32)(bnz >> 32);
        }
    }
    __syncthreads();
    const int o = tid;
    const u32* wsrow = wsm + (size_t)o * 2 * W;
    const u32* wnzrow = wnzm + (size_t)o * 2 * W;
    u32 wds[W], wdnz[W], wcs[W], wcnz[W];
#pragma unroll
    for (int w = 0; w < W; ++w) {
        wds[w] = wsrow[w];      wcs[w] = wsrow[W + w];
        wdnz[w] = wnzrow[w];    wcnz[w] = wnzrow[W + w];
    }
    int cdot = 0;
#pragma unroll
    for (int w = 0; w < W; ++w) {
        u32 nzb = ctr_nz[w] & wcnz[w];
        u32 neg = (ctr_s[w] ^ wcs[w]) & nzb;
        cdot += __popc(nzb) - 2 * __popc(neg);
    }
    const float as = __fmul_rn(aa[o], ssc[o]);
    const float bo = bbi[o], po = pp[o];
    float best = -3.4e38f;
    for (int k = 0; k < KNB; ++k) {
        int dot = cdot;
#pragma unroll
        for (int w = 0; w < W; ++w) {
            u32 nzb = dfnz[k][w] & wdnz[w];
            u32 neg = (dfs[k][w] ^ wds[w]) & nzb;
            dot += __popc(nzb) - 2 * __popc(neg);
        }
        float y = __fadd_rn(__fmul_rn((float)dot, as), bo);
        y = y > 0.f ? y : __fmul_rn(po, y);
        best = fmaxf(best, y);
    }
    if (WRITEF) yR[((size_t)b * N + n) * COUT + o] = best;
    u64 bs = __ballot(best < 0.f);
    u64 bnz = __ballot(best != 0.f);
    if ((tid & 63) == 0) {
        int w = woff + (tid >> 5);
        xss[(size_t)(b * 16 + w) * N + n] = (u32)bs;
        xss[(size_t)(b * 16 + w + 1) * N + n] = (u32)(bs >> 32);
        xnzs[(size_t)(b * 16 + w) * N + n] = (u32)bnz;
        xnzs[(size_t)(b * 16 + w + 1) * N + n] = (u32)(bnz >> 32);
    }
}

// ---------------- conv1d bitplane popcount + fused pooling ----------------

__global__ __launch_bounds__(256) void conv1d_bin_pool_kernel(
    const u32* __restrict__ xs, const u32* __restrict__ xnz, const u32* __restrict__ w5s,
    const u32* __restrict__ w5nz, const float* __restrict__ aa, const float* __restrict__ ssc,
    const float* __restrict__ bbi, const float* __restrict__ pp, float* __restrict__ pmax,
    float* __restrict__ psum) {
    const int b = blockIdx.y;
    const int otile = blockIdx.x & 3;
    const int nq = blockIdx.x >> 2;  // 0..15
    const int tid = threadIdx.x;
    const int o = otile * 256 + tid;
    __shared__ u32 shs[64][21];
    __shared__ u32 shnz[64][21];
    u32 ws[16], wnz[16];
#pragma unroll
    for (int w = 0; w < 16; ++w) {
        ws[w] = w5s[(size_t)o * 16 + w];
        wnz[w] = w5nz[(size_t)o * 16 + w];
    }
    const int nbase = nq * 64;
    for (int t = tid; t < 16 * 64; t += 256) {
        int w = t >> 6, nl = t & 63;
        shs[nl][w] = xs[((size_t)b * 16 + w) * N + nbase + nl];
        shnz[nl][w] = xnz[((size_t)b * 16 + w) * N + nbase + nl];
    }
    __syncthreads();
    const float as = __fmul_rn(aa[o], ssc[o]);
    const float bo = bbi[o], po = pp[o];
    float m = -3.4e38f, sum = 0.f;
    for (int nl = 0; nl < 64; ++nl) {
        int dot = 0;
#pragma unroll
        for (int w = 0; w < 16; ++w) {
            u32 nzb = shnz[nl][w] & wnz[w];
            u32 neg = (shs[nl][w] ^ ws[w]) & nzb;
            dot += __popc(nzb) - 2 * __popc(neg);
        }
        float y = __fadd_rn(__fmul_rn((float)dot, as), bo);
        y = y > 0.f ? y : __fmul_rn(po, y);
        m = fmaxf(m, y);
        sum = __fadd_rn(sum, y);  // exact: quarter-integers
    }
    pmax[((size_t)b * 1024 + o) * 16 + nq] = m;
    psum[((size_t)b * 1024 + o) * 16 + nq] = sum;
}

__global__ __launch_bounds__(256) void pool_reduce_kernel(const float* __restrict__ pmax,
                                                          const float* __restrict__ psum,
                                                          float* __restrict__ pooled) {
    int i = blockIdx.x * blockDim.x + threadIdx.x;
    if (i >= B * 1024) return;
    int b = i >> 10, o = i & 1023;
    const float* pm = pmax + (size_t)i * 16;
    const float* ps = psum + (size_t)i * 16;
    float m = -3.4e38f, s = 0.f;
    for (int t = 0; t < 16; ++t) { m = fmaxf(m, pm[t]); s = __fadd_rn(s, ps[t]); }
    pooled[(size_t)b * 2048 + o] = m;
    pooled[(size_t)b * 2048 + 1024 + o] = __fmul_rn(s, (1.f / 1024.f));
}

// pack pooled (B x 2048) into ternary bitplanes: B x 64 words
__global__ __launch_bounds__(256) void pack_pooled_kernel(const float* __restrict__ pooled,
                                                          u32* __restrict__ s,
                                                          u32* __restrict__ nz) {
    int i = blockIdx.x * blockDim.x + threadIdx.x;
    if (i >= B * 64) return;
    const float* p = pooled + (size_t)i * 32;
    u32 sb = 0, nb = 0;
    for (int j = 0; j < 32; ++j) {
        float v = p[j];
        if (v < 0.f) sb |= (1u << j);
        if (v != 0.f) nb |= (1u << j);
    }
    s[i] = sb;
    nz[i] = nb;
}

// ---------------- bitpacked lin1 / lin2 / lin3 (UNCHANGED) ----------------

__global__ __launch_bounds__(256) void lin1_bin_kernel(
    const u32* __restrict__ xs, const u32* __restrict__ xnz, const u32* __restrict__ wls,
    const u32* __restrict__ wlnz, const float* __restrict__ aa, const float* __restrict__ ssc,
    const float* __restrict__ bbi, const float* __restrict__ pp, u32* __restrict__ l1s,
    u32* __restrict__ l1nz) {
    const int b = blockIdx.y, otile = blockIdx.x, tid = threadIdx.x;
    const int o = otile * 256 + tid;
    __shared__ u32 sxs[64], sxnz[64];
    if (tid < 64) { sxs[tid] = xs[b * 64 + tid]; sxnz[tid] = xnz[b * 64 + tid]; }
    __syncthreads();
    const u32* wsr = wls + (size_t)o * 64;
    const u32* wnzr = wlnz + (size_t)o * 64;
    int dot = 0;
#pragma unroll
    for (int w = 0; w < 64; ++w) {
        u32 nzb = sxnz[w] & wnzr[w];
        u32 neg = (sxs[w] ^ wsr[w]) & nzb;
        dot += __popc(nzb) - 2 * __popc(neg);
    }
    float y = __fadd_rn(__fmul_rn((float)dot, __fmul_rn(aa[o], ssc[o])), bbi[o]);
    y = y > 0.f ? y : __fmul_rn(pp[o], y);
    u64 bs = __ballot(y < 0.f);
    u64 bnz = __ballot(y != 0.f);
    if ((tid & 63) == 0) {
        int w = otile * 8 + (tid >> 5);
        l1s[b * 16 + w] = (u32)bs;       l1s[b * 16 + w + 1] = (u32)(bs >> 32);
        l1nz[b * 16 + w] = (u32)bnz;     l1nz[b * 16 + w + 1] = (u32)(bnz >> 32);
    }
}

__global__ __launch_bounds__(256) void lin2_bin_kernel(
    const u32* __restrict__ xs, const u32* __restrict__ xnz, const u32* __restrict__ wls,
    const u32* __restrict__ wlnz, const float* __restrict__ aa, const float* __restrict__ ssc,
    const float* __restrict__ bbi, const float* __restrict__ pp, float* __restrict__ out) {
    const int b = blockIdx.x, o = threadIdx.x;
    __shared__ u32 sxs[16], sxnz[16];
    if (o < 16) { sxs[o] = xs[b * 16 + o]; sxnz[o] = xnz[b * 16 + o]; }
    __syncthreads();
    const u32* wsr = wls + (size_t)o * 16;
    const u32* wnzr = wlnz + (size_t)o * 16;
    int dot = 0;
#pragma unroll
    for (int w = 0; w < 16; ++w) {
        u32 nzb = sxnz[w] & wnzr[w];
        u32 neg = (sxs[w] ^ wsr[w]) & nzb;
        dot += __popc(nzb) - 2 * __popc(neg);
    }
    float y = __fadd_rn(__fmul_rn((float)dot, __fmul_rn(aa[o], ssc[o])), bbi[o]);
    out[b * 256 + o] = y > 0.f ? y : __fmul_rn(pp[o], y);
}

__global__ __launch_bounds__(64) void lin3_kernel(const float* __restrict__ xin,
                                                  const float* __restrict__ W,
                                                  const float* __restrict__ ssc,
                                                  const float* __restrict__ bbi,
                                                  float* __restrict__ out) {
    int b = blockIdx.x, j = threadIdx.x;
    if (j >= 40) return;
    const float* wrow = W + j * 256;
    const float* xb = xin + b * 256;
    double acc = 0.0;
    for (int c = 0; c < 256; ++c) acc = fma((double)xb[c], (double)wrow[c], acc);
    out[b * 40 + j] = __fadd_rn(__fmul_rn((float)acc, ssc[j]), bbi[j]);
}

extern "C" void kernel_launch(void* const* d_in, const int* in_sizes, int n_in, void* d_out,
                              int out_size, void* d_ws, size_t ws_size, hipStream_t stream) {
    float* outp = (float*)d_out;
    auto sentinel = [&](float code) {
        sentinel_kernel<<<(640 + 255) / 256, 256, 0, stream>>>(outp, 640, code * 1.0e6f);
    };
    if (n_in != 39) { sentinel(1.f); return; }
    static const int expect[39] = {
        16 * 3 * 1024,
        64 * 6, 64, 64, 64, 64,
        64 * 128, 64, 64, 64, 64,
        128 * 128, 128, 128, 128, 128,
        256 * 256, 256, 256, 256, 256,
        1024 * 512, 1024, 1024, 1024, 1024,
        512 * 2048, 512, 512, 512, 512,
        256 * 512, 256, 256, 256, 256,
        40 * 256, 40, 40
    };
    for (int i = 0; i < 39; ++i)
        if (in_sizes[i] != expect[i]) { sentinel(2.f); return; }
    if (out_size != 640) { sentinel(3.f); return; }

    const float* x0 = (const float*)d_in[0];
    const float *w1 = (const float*)d_in[1], *a1 = (const float*)d_in[2],
                *s1 = (const float*)d_in[3], *b1 = (const float*)d_in[4],
                *p1 = (const float*)d_in[5];
    const float *a2 = (const float*)d_in[7], *s2 = (const float*)d_in[8],
                *b2 = (const float*)d_in[9], *p2 = (const float*)d_in[10];
    const float *a3 = (const float*)d_in[12], *s3 = (const float*)d_in[13],
                *b3 = (const float*)d_in[14], *p3 = (const float*)d_in[15];
    const float *a4 = (const float*)d_in[17], *s4 = (const float*)d_in[18],
                *b4 = (const float*)d_in[19], *p4 = (const float*)d_in[20];
    const float *a5 = (const float*)d_in[22], *s5 = (const float*)d_in[23],
                *b5 = (const float*)d_in[24], *p5 = (const float*)d_in[25];
    const float *w2 = (const float*)d_in[6], *w3 = (const float*)d_in[11],
                *w4 = (const float*)d_in[16], *w5 = (const float*)d_in[21];
    const float *wl1 = (const float*)d_in[26], *al1 = (const float*)d_in[27],
                *sl1 = (const float*)d_in[28], *bl1 = (const float*)d_in[29],
                *pl1 = (const float*)d_in[30];
    const float *wl2 = (const float*)d_in[31], *al2 = (const float*)d_in[32],
                *sl2 = (const float*)d_in[33], *bl2 = (const float*)d_in[34],
                *pl2 = (const float*)d_in[35];
    const float *wl3 = (const float*)d_in[36], *sl3 = (const float*)d_in[37],
                *bl3 = (const float*)d_in[38];

    char* ws = (char*)d_ws;
    size_t off = 0;
    auto alloc = [&](size_t bytes) -> void* {
        void* p = ws + off;
        off += (bytes + 255) & ~(size_t)255;
        return p;
    };
    float* xcat = (float*)alloc((size_t)B * 256 * N * 4);
    float* yA = (float*)alloc((size_t)B * N * 128 * 4);
    float* yB = (float*)alloc((size_t)B * N * 64 * 4);
    float* x0R = (float*)alloc((size_t)B * N * 3 * 4);
    int* idxb = (int*)alloc((size_t)B * N * KNB * 4);
    float* sqb = (float*)alloc((size_t)B * N * 4);
    u32* w2s_ = (u32*)alloc(64 * 4 * 4);     u32* w2nz_ = (u32*)alloc(64 * 4 * 4);
    u32* w3s_ = (u32*)alloc(128 * 4 * 4);    u32* w3nz_ = (u32*)alloc(128 * 4 * 4);
    u32* w4s_ = (u32*)alloc(256 * 8 * 4);    u32* w4nz_ = (u32*)alloc(256 * 8 * 4);
    u32* w5s_ = (u32*)alloc(1024 * 16 * 4);  u32* w5nz_ = (u32*)alloc(1024 * 16 * 4);
    u32* wl1s_ = (u32*)alloc(512 * 64 * 4);  u32* wl1nz_ = (u32*)alloc(512 * 64 * 4);
    u32* wl2s_ = (u32*)alloc(256 * 16 * 4);  u32* wl2nz_ = (u32*)alloc(256 * 16 * 4);
    u32* xss = (u32*)alloc((size_t)B * 16 * N * 4);
    u32* xnzs = (u32*)alloc((size_t)B * 16 * N * 4);
    u32* pls = (u32*)alloc((size_t)B * 64 * 4);
    u32* plnz = (u32*)alloc((size_t)B * 64 * 4);
    u32* l1s = (u32*)alloc((size_t)B * 16 * 4);
    u32* l1nz = (u32*)alloc((size_t)B * 16 * 4);
    float* pmax = (float*)alloc((size_t)B * 1024 * 16 * 4);
    float* psum = (float*)alloc((size_t)B * 1024 * 16 * 4);
    float* pooled = (float*)alloc((size_t)B * 2048 * 4);
    float* l2o = (float*)alloc((size_t)B * 256 * 4);
    if (off > ws_size) { sentinel(4.f); return; }

    pack_rows_kernel<<<1, 256, 0, stream>>>(w2, 64, 128, w2s_, w2nz_);
    pack_rows_kernel<<<2, 256, 0, stream>>>(w3, 128, 128, w3s_, w3nz_);
    pack_rows_kernel<<<8, 256, 0, stream>>>(w4, 256, 256, w4s_, w4nz_);
    pack_rows_kernel<<<64, 256, 0, stream>>>(w5, 1024, 512, w5s_, w5nz_);
    pack_rows_kernel<<<128, 256, 0, stream>>>(wl1, 512, 2048, wl1s_, wl1nz_);
    pack_rows_kernel<<<16, 256, 0, stream>>>(wl2, 256, 512, wl2s_, wl2nz_);

    dim3 gnb(N, B);
    const int gknn = (N / 16) * B;  // 1024 blocks, XCD-swizzled inside the kernel
    const int npt = (B * N + 255) / 256;
    // ---- layer 1 ----
    sq_np_kernel<3><<<npt, 256, 0, stream>>>(x0, 3, 0, sqb);
    transpose3_kernel<<<npt, 256, 0, stream>>>(x0, x0R);
    knn_radix4_kernel<3><<<gknn, 256, 0, stream>>>(x0, 3, 0, sqb, idxb);
    edgeconv1_kernel<3, 64>
        <<<gnb, 64, 0, stream>>>(x0R, idxb, w1, a1, s1, b1, p1, yA, xss, xnzs, 0);
    transpose_rm2cm_kernel<<<dim3(16, 1, B), 256, 0, stream>>>(yA, 64, xcat, 0);
    // ---- layer 2 ----
    sq_np_kernel<64><<<npt, 256, 0, stream>>>(xcat, 256, 0, sqb);
    knn_radix4_kernel<64><<<gknn, 256, 0, stream>>>(xcat, 256, 0, sqb, idxb);
    edgeconv_bin2_kernel<64, 64, true>
        <<<gnb, 64, 0, stream>>>(yA, idxb, w2s_, w2nz_, a2, s2, b2, p2, yB, xss, xnzs, 2);
    transpose_rm2cm_kernel<<<dim3(16, 1, B), 256, 0, stream>>>(yB, 64, xcat, 64);
    // ---- layer 3 ----
    sq_np_kernel<64><<<npt, 256, 0, stream>>>(xcat, 256, 64, sqb);
    knn_radix4_kernel<64><<<gknn, 256, 0, stream>>>(xcat, 256, 64, sqb, idxb);
    edgeconv_bin2_kernel<64, 128, true>
        <<<gnb, 128, 0, stream>>>(yB, idxb, w3s_, w3nz_, a3, s3, b3, p3, yA, xss, xnzs, 4);
    transpose_rm2cm_kernel<<<dim3(16, 2, B), 256, 0, stream>>>(yA, 128, xcat, 128);
    // ---- layer 4 ----
    sq_np_kernel<128><<<npt, 256, 0, stream>>>(xcat, 256, 128, sqb);
    knn_radix4_kernel<128><<<gknn, 256, 0, stream>>>(xcat, 256, 128, sqb, idxb);
    edgeconv_bin2_kernel<128, 256, false>
        <<<gnb, 256, 0, stream>>>(yA, idxb, w4s_, w4nz_, a4, s4, b4, p4, nullptr, xss, xnzs, 8);
    // ---- conv1d + pooling + heads ----
    conv1d_bin_pool_kernel<<<dim3(64, B), 256, 0, stream>>>(xss, xnzs, w5s_, w5nz_, a5, s5, b5,
                                                            p5, pmax, psum);
    pool_reduce_kernel<<<(B * 1024 + 255) / 256, 256, 0, stream>>>(pmax, psum, pooled);
    pack_pooled_kernel<<<(B * 64 + 255) / 256, 256, 0, stream>>>(pooled, pls, plnz);
    lin1_bin_kernel<<<dim3(2, B), 256, 0, stream>>>(pls, plnz, wl1s_, wl1nz_, al1, sl1, bl1, pl1,
                                                    l1s, l1nz);
    lin2_bin_kernel<<<B, 256, 0, stream>>>(l1s, l1nz, wl2s_, wl2nz_, al2, sl2, bl2, pl2, l2o);
    lin3_kernel<<<B, 64, 0, stream>>>(l2o, wl3, sl3, bl3, outp);
}